// Round 3
// baseline (495.158 us; speedup 1.0000x reference)
//
#include <hip/hip_runtime.h>
#include <math.h>

#define NB 32
#define C 256
#define H 64
#define W 64
#define HW 4096
#define KT 25  // 25 unfold tiles of 64 o-rows

// ===========================================================================
// MEASUREMENT ROUND: kernels are byte-identical to round 2. The launcher
// replays the (pure, idempotent) 4-kernel sequence 3x so that
//   slope = (dur_r3 - dur_r2) / 2
// isolates the true per-sequence kernel cost from any fixed timed overhead
// (poison fills, harness fixed cost). Correctness is unchanged: every kernel
// is a pure function of inputs / earlier workspace tensors.
// ===========================================================================

// ---------------------------------------------------------------------------
// KA: three independent preps packed into one launch.
//   bid <  157 : WW[o][kk] = sum_c W10[o][c] * W8[c][kk]
//   bid == 157 : w2bar[c]  = mean_o W2[o][c]
//   bid >= 158 : t3 (relu-max per (n,c) plane), ONE WAVE PER PLANE
// ---------------------------------------------------------------------------
__global__ __launch_bounds__(256) void ka_prep(
    const float* __restrict__ x, const float* __restrict__ W2,
    const float* __restrict__ W8, const float* __restrict__ W10,
    float* __restrict__ w2bar, float* __restrict__ t3,
    float* __restrict__ WW) {
  int bid = blockIdx.x, tid = threadIdx.x;
  if (bid < 157) {
    __shared__ float s8[6400];
    for (int i = tid; i < 6400; i += 256) s8[i] = W8[i];
    __syncthreads();
    int idx = bid * 256 + tid;
    if (idx < 40000) {
      int o = idx / 25, kk = idx - o * 25;
      const float* wrow = W10 + (size_t)o * 256;
      float acc = 0.f;
#pragma unroll 8
      for (int c = 0; c < 256; ++c) acc = fmaf(wrow[c], s8[c * 25 + kk], acc);
      WW[idx] = acc;
    }
  } else if (bid == 157) {
    float s = 0.f;
#pragma unroll 8
    for (int o = 0; o < 256; ++o) s += W2[o * 256 + tid];
    w2bar[tid] = s * (1.f / 256.f);
  } else {
    int item = (bid - 158) * 4 + (tid >> 6);
    int lane = tid & 63;
    const float4* xv = (const float4*)(x + (size_t)item * HW);
    float m = -3.4e38f;
#pragma unroll
    for (int i = 0; i < 16; ++i) {
      float4 v = xv[i * 64 + lane];
      m = fmaxf(m, fmaxf(fmaxf(v.x, v.y), fmaxf(v.z, v.w)));
    }
#pragma unroll
    for (int off = 32; off > 0; off >>= 1)
      m = fmaxf(m, __shfl_down(m, off, 64));
    if (lane == 0) t3[item] = fmaxf(m, 0.f);
  }
}

// ---------------------------------------------------------------------------
// KB: t5/t13 streaming pass over x; 1024 blocks (n, 32 position-chunks of
// 128), c split in half across the block.
// ---------------------------------------------------------------------------
__global__ __launch_bounds__(256) void kb_t5t13(
    const float* __restrict__ x, const float* __restrict__ w2bar,
    const float* __restrict__ t3, const float* __restrict__ p4,
    const float* __restrict__ p13, float* __restrict__ t5,
    float* __restrict__ t13) {
  int bid = blockIdx.x, tid = threadIdx.x;
  int n = bid >> 5;
  int pc = bid & 31;
  int half = tid >> 7;
  int lp = tid & 127;
  int p = pc * 128 + lp;
  __shared__ float sw[256];
  __shared__ float st[256];
  __shared__ float r5[256];
  __shared__ float r9[256];
  sw[tid] = w2bar[tid];
  st[tid] = t3[n * 256 + tid];
  __syncthreads();
  const float* xp = x + (size_t)n * C * HW + (size_t)half * 128 * HW + p;
  float accs = 0.f, acc9 = 0.f;
#pragma unroll 16
  for (int c = 0; c < 128; ++c) {
    float v = xp[(size_t)c * HW];
    accs = fmaf(sw[half * 128 + c], fmaxf(v, 0.f), accs);
    acc9 = fmaf(st[half * 128 + c], v, acc9);
  }
  r5[tid] = accs;
  r9[tid] = acc9;
  __syncthreads();
  if (tid < 128) {
    int pp = pc * 128 + tid;
    float as = r5[tid] + r5[tid + 128];
    float a9 = r9[tid] + r9[tid + 128];
    t5[n * HW + pp] = p4[pp] * as;
    t13[n * HW + pp] = p13[pp] * a9;
  }
}

// ---------------------------------------------------------------------------
// KC: per (n,k) tile: stage t5 + WW rows; unfold col-max -> t7; K=25 GEMM;
// t6 + gelu; max over h -> part[n][k][w].
// ---------------------------------------------------------------------------
__global__ __launch_bounds__(256) void kc_tile(
    const float* __restrict__ t5g, const float* __restrict__ WW,
    float* __restrict__ part) {
  int n = blockIdx.x / KT;
  int k = blockIdx.x - n * KT;
  int ki = k / 5, kj = k - ki * 5;
  int tid = threadIdx.x;
  int wg = tid & 15, w0 = wg * 4;
  int rg = tid >> 4, h0 = rg * 4;
  __shared__ float s5[HW];
  __shared__ float ww[64 * 25];
  __shared__ float t7s[25 * 64];
  __shared__ float cm[5 * 64];

  const float4* t5v = (const float4*)(t5g + n * HW);
  float4* s5v = (float4*)s5;
#pragma unroll
  for (int i = 0; i < 4; ++i) s5v[i * 256 + tid] = t5v[i * 256 + tid];
  const float* wwsrc = WW + (size_t)k * 64 * 25;
  for (int i = tid; i < 1600; i += 256) ww[i] = wwsrc[i];
  __syncthreads();

  for (int idx = tid; idx < 5 * 64; idx += 256) {
    int kii = idx >> 6, wp = idx & 63;
    int lo = max(0, 3 * kii - 6), hi = min(63, 3 * kii + 57);
    float m = (kii == 2) ? -3.4e38f : 0.0f;
    for (int hp = lo; hp <= hi; ++hp) m = fmaxf(m, s5[hp * 64 + wp]);
    cm[kii * 64 + wp] = m;
  }
  __syncthreads();
  for (int idx = tid; idx < 25 * 64; idx += 256) {
    int kk = idx >> 6, w = idx & 63;
    int kki = kk / 5, kkj = kk - kki * 5;
    int wp = w + 3 * kkj - 6;
    t7s[kk * 64 + w] = (wp >= 0 && wp < 64) ? cm[kki * 64 + wp] : 0.0f;
  }
  __syncthreads();

  float4 acc[4];
#pragma unroll
  for (int j = 0; j < 4; ++j) acc[j] = make_float4(0.f, 0.f, 0.f, 0.f);
#pragma unroll
  for (int kk = 0; kk < 25; ++kk) {
    float4 tv = *(const float4*)&t7s[kk * 64 + w0];
#pragma unroll
    for (int j = 0; j < 4; ++j) {
      float a = ww[(h0 + j) * 25 + kk];
      acc[j].x = fmaf(a, tv.x, acc[j].x);
      acc[j].y = fmaf(a, tv.y, acc[j].y);
      acc[j].z = fmaf(a, tv.z, acc[j].z);
      acc[j].w = fmaf(a, tv.w, acc[j].w);
    }
  }

  int hpb = 3 * ki - 6, wpb = 3 * kj - 6;
  float pm[4] = {-3.4e38f, -3.4e38f, -3.4e38f, -3.4e38f};
#pragma unroll
  for (int j = 0; j < 4; ++j) {
    int hp = h0 + j + hpb;
    float av[4] = {acc[j].x, acc[j].y, acc[j].z, acc[j].w};
#pragma unroll
    for (int e = 0; e < 4; ++e) {
      int wp = w0 + e + wpb;
      float t6v = (hp >= 0 && hp < 64 && wp >= 0 && wp < 64)
                      ? s5[hp * 64 + wp] : 0.0f;
      float xg = av[e];
      float gl = 0.5f * xg * (1.0f + erff(xg * 0.70710678118654752f));
      pm[e] = fmaxf(pm[e], t6v + gl);
    }
  }
  __syncthreads();
  float* red = t7s;
#pragma unroll
  for (int e = 0; e < 4; ++e) red[rg * 64 + w0 + e] = pm[e];
  __syncthreads();
  if (tid < 64) {
    float m = -3.4e38f;
#pragma unroll
    for (int g = 0; g < 16; ++g) m = fmaxf(m, red[g * 64 + tid]);
    part[(n * KT + k) * 64 + tid] = m;
  }
}

// ---------------------------------------------------------------------------
// KD: t17 recomputed per block from part + output.
// ---------------------------------------------------------------------------
__global__ __launch_bounds__(256) void kd_out(
    const float* __restrict__ part, const float* __restrict__ t13,
    const float* __restrict__ W18, float* __restrict__ out) {
  int bid = blockIdx.x, tid = threadIdx.x;
  int n = bid >> 5, cg8 = bid & 31;
  __shared__ float ps[1600];
  __shared__ float Mb[64];
  __shared__ float t17b[64];
  __shared__ float t13s[4096];
  const float* pp = part + (size_t)n * KT * 64;
  for (int i = tid; i < 1600; i += 256) ps[i] = pp[i];
  const float4* t13v = (const float4*)(t13 + (size_t)n * HW);
  float4* t13sv = (float4*)t13s;
#pragma unroll
  for (int i = 0; i < 4; ++i) t13sv[i * 256 + tid] = t13v[i * 256 + tid];
  __syncthreads();
  if (tid < 64) {
    float m = -3.4e38f;
#pragma unroll
    for (int t = 0; t < KT; ++t) m = fmaxf(m, ps[t * 64 + tid]);
    Mb[tid] = expf(m);
  }
  __syncthreads();
  if (tid < 64) {
    float s = 0.f;
#pragma unroll
    for (int j = 0; j < 7; ++j) {
      int wp = tid + 3 * j - 9;
      if (wp >= 0 && wp < 64) s += Mb[wp];
    }
    t17b[tid] = s * (1.0f / 7.0f);
  }
  __syncthreads();
  const float4* t17v = (const float4*)t17b;
#pragma unroll
  for (int i = 0; i < 8; ++i) {
    int c = cg8 * 8 + i;
    float4* outv = (float4*)(out + (size_t)(n * 256 + c) * HW);
#pragma unroll
    for (int it = 0; it < 4; ++it) {
      int idx = it * 256 + tid;
      int h = idx >> 4;
      int w4 = idx & 15;
      float w18 = W18[c * 64 + h];
      float4 a = t13sv[idx];
      float4 tt = t17v[w4];
      float4 o;
      o.x = a.x - w18 * tt.x;
      o.y = a.y - w18 * tt.y;
      o.z = a.z - w18 * tt.z;
      o.w = a.w - w18 * tt.w;
      outv[idx] = o;
    }
  }
}

// ---------------------------------------------------------------------------
extern "C" void kernel_launch(void* const* d_in, const int* in_sizes, int n_in,
                              void* d_out, int out_size, void* d_ws,
                              size_t ws_size, hipStream_t stream) {
  const float* x   = (const float*)d_in[0];
  const float* W2  = (const float*)d_in[1];
  const float* W8  = (const float*)d_in[2];
  const float* W10 = (const float*)d_in[3];
  const float* W18 = (const float*)d_in[4];
  const float* p4  = (const float*)d_in[5];
  const float* p13 = (const float*)d_in[6];
  float* out = (float*)d_out;

  float* ws    = (float*)d_ws;
  float* w2bar = ws;                   // 256
  float* t3    = w2bar + 256;          // 32*256
  float* t5    = t3 + NB * C;          // 32*4096
  float* t13   = t5 + NB * HW;         // 32*4096
  float* WW    = t13 + NB * HW;        // 1600*25
  float* part  = WW + 40000;           // 32*25*64

  // Replay the pure 4-kernel sequence 3x: slope vs round-2 dur isolates the
  // true kernel cost from fixed timed overhead. Results are identical to a
  // single pass (all kernels are pure functions of inputs / prior tensors).
  for (int rep = 0; rep < 3; ++rep) {
    ka_prep<<<dim3(158 + 2048), dim3(256), 0, stream>>>(x, W2, W8, W10, w2bar,
                                                        t3, WW);
    kb_t5t13<<<dim3(NB * 32), dim3(256), 0, stream>>>(x, w2bar, t3, p4, p13,
                                                      t5, t13);
    kc_tile<<<dim3(NB * KT), dim3(256), 0, stream>>>(t5, WW, part);
    kd_out<<<dim3(NB * 32), dim3(256), 0, stream>>>(part, t13, W18, out);
  }
}

// Round 4
// 303.829 us; speedup vs baseline: 1.6297x; 1.6297x over previous
//
#include <hip/hip_runtime.h>
#include <math.h>

#define NB 32
#define C 256
#define H 64
#define W 64
#define HW 4096
#define KT 25  // 25 unfold tiles of 64 o-rows

// Established by the round-3 differential probe: kernel sequence ~98 us,
// fixed timed overhead (harness poison fills) ~201 us. Floor ~= 260-270 us.

// ---------------------------------------------------------------------------
// KA: three independent preps packed into one launch.
//   bid <  157 : WW[o][kk] = sum_c W10[o][c] * W8[c][kk]
//   bid == 157 : w2bar[c]  = mean_o W2[o][c]
//   bid >= 158 : t3 (relu-max per (n,c) plane), ONE WAVE PER PLANE
// ---------------------------------------------------------------------------
__global__ __launch_bounds__(256) void ka_prep(
    const float* __restrict__ x, const float* __restrict__ W2,
    const float* __restrict__ W8, const float* __restrict__ W10,
    float* __restrict__ w2bar, float* __restrict__ t3,
    float* __restrict__ WW) {
  int bid = blockIdx.x, tid = threadIdx.x;
  if (bid < 157) {
    __shared__ float s8[6400];
    for (int i = tid; i < 6400; i += 256) s8[i] = W8[i];
    __syncthreads();
    int idx = bid * 256 + tid;
    if (idx < 40000) {
      int o = idx / 25, kk = idx - o * 25;
      const float* wrow = W10 + (size_t)o * 256;
      float acc = 0.f;
#pragma unroll 8
      for (int c = 0; c < 256; ++c) acc = fmaf(wrow[c], s8[c * 25 + kk], acc);
      WW[idx] = acc;
    }
  } else if (bid == 157) {
    float s = 0.f;
#pragma unroll 8
    for (int o = 0; o < 256; ++o) s += W2[o * 256 + tid];
    w2bar[tid] = s * (1.f / 256.f);
  } else {
    int item = (bid - 158) * 4 + (tid >> 6);
    int lane = tid & 63;
    const float4* xv = (const float4*)(x + (size_t)item * HW);
    float m = -3.4e38f;
#pragma unroll
    for (int i = 0; i < 16; ++i) {
      float4 v = xv[i * 64 + lane];
      m = fmaxf(m, fmaxf(fmaxf(v.x, v.y), fmaxf(v.z, v.w)));
    }
#pragma unroll
    for (int off = 32; off > 0; off >>= 1)
      m = fmaxf(m, __shfl_down(m, off, 64));
    if (lane == 0) t3[item] = fmaxf(m, 0.f);
  }
}

// ---------------------------------------------------------------------------
// KB v2: t5/t13 second pass over x (L3-resident), FLOAT4 loads.
// 1024 blocks = (n, 32 chunks of 128 positions). 8-way c-split: c-slice
// cs = tid>>5 covers c in [cs*32, cs*32+32); 32 lanes each own one float4
// (4 positions). Per 32-lane group: 512 B contiguous per load, 32 c-iters.
// LDS tree-reduce over the 8 slices, then scale by p4/p13 and store.
// ---------------------------------------------------------------------------
__global__ __launch_bounds__(256) void kb_t5t13(
    const float* __restrict__ x, const float* __restrict__ w2bar,
    const float* __restrict__ t3, const float* __restrict__ p4,
    const float* __restrict__ p13, float* __restrict__ t5,
    float* __restrict__ t13) {
  int bid = blockIdx.x, tid = threadIdx.x;
  int n = bid >> 5;
  int pc = bid & 31;           // 128-position chunk
  int cs = tid >> 5;           // c-slice 0..7
  int l32 = tid & 31;          // float4 index within chunk
  __shared__ float sw[256];
  __shared__ float st[256];
  __shared__ float4 red5[8][32];
  __shared__ float4 red9[8][32];
  sw[tid] = w2bar[tid];
  st[tid] = t3[n * 256 + tid];
  __syncthreads();
  const float4* xq = (const float4*)(x + (size_t)n * C * HW);
  int qbase = pc * 32 + l32;   // float4 index within a 4096-pos plane row
  float4 a5 = make_float4(0.f, 0.f, 0.f, 0.f);
  float4 a9 = make_float4(0.f, 0.f, 0.f, 0.f);
#pragma unroll 8
  for (int ci = 0; ci < 32; ++ci) {
    int c = cs * 32 + ci;
    float4 v = xq[(size_t)c * 1024 + qbase];
    float wv = sw[c], tv = st[c];
    a5.x = fmaf(wv, fmaxf(v.x, 0.f), a5.x);
    a5.y = fmaf(wv, fmaxf(v.y, 0.f), a5.y);
    a5.z = fmaf(wv, fmaxf(v.z, 0.f), a5.z);
    a5.w = fmaf(wv, fmaxf(v.w, 0.f), a5.w);
    a9.x = fmaf(tv, v.x, a9.x);
    a9.y = fmaf(tv, v.y, a9.y);
    a9.z = fmaf(tv, v.z, a9.z);
    a9.w = fmaf(tv, v.w, a9.w);
  }
  red5[cs][l32] = a5;
  red9[cs][l32] = a9;
  __syncthreads();
  if (tid < 32) {
    float4 s = red5[0][tid];
#pragma unroll
    for (int g = 1; g < 8; ++g) {
      float4 r = red5[g][tid];
      s.x += r.x; s.y += r.y; s.z += r.z; s.w += r.w;
    }
    float4 pv = ((const float4*)p4)[pc * 32 + tid];
    s.x *= pv.x; s.y *= pv.y; s.z *= pv.z; s.w *= pv.w;
    ((float4*)(t5 + n * HW))[pc * 32 + tid] = s;
  } else if (tid < 64) {
    int l = tid - 32;
    float4 s = red9[0][l];
#pragma unroll
    for (int g = 1; g < 8; ++g) {
      float4 r = red9[g][l];
      s.x += r.x; s.y += r.y; s.z += r.z; s.w += r.w;
    }
    float4 pv = ((const float4*)p13)[pc * 32 + l];
    s.x *= pv.x; s.y *= pv.y; s.z *= pv.z; s.w *= pv.w;
    ((float4*)(t13 + n * HW))[pc * 32 + l] = s;
  }
}

// ---------------------------------------------------------------------------
// KC: per (n,k) tile: stage t5 + WW rows; unfold col-max -> t7; K=25 GEMM;
// t6 + gelu; max over h -> part[n][k][w].
// ---------------------------------------------------------------------------
__global__ __launch_bounds__(256) void kc_tile(
    const float* __restrict__ t5g, const float* __restrict__ WW,
    float* __restrict__ part) {
  int n = blockIdx.x / KT;
  int k = blockIdx.x - n * KT;
  int ki = k / 5, kj = k - ki * 5;
  int tid = threadIdx.x;
  int wg = tid & 15, w0 = wg * 4;
  int rg = tid >> 4, h0 = rg * 4;
  __shared__ float s5[HW];
  __shared__ float ww[64 * 25];
  __shared__ float t7s[25 * 64];
  __shared__ float cm[5 * 64];

  const float4* t5v = (const float4*)(t5g + n * HW);
  float4* s5v = (float4*)s5;
#pragma unroll
  for (int i = 0; i < 4; ++i) s5v[i * 256 + tid] = t5v[i * 256 + tid];
  const float* wwsrc = WW + (size_t)k * 64 * 25;
  for (int i = tid; i < 1600; i += 256) ww[i] = wwsrc[i];
  __syncthreads();

  for (int idx = tid; idx < 5 * 64; idx += 256) {
    int kii = idx >> 6, wp = idx & 63;
    int lo = max(0, 3 * kii - 6), hi = min(63, 3 * kii + 57);
    float m = (kii == 2) ? -3.4e38f : 0.0f;
    for (int hp = lo; hp <= hi; ++hp) m = fmaxf(m, s5[hp * 64 + wp]);
    cm[kii * 64 + wp] = m;
  }
  __syncthreads();
  for (int idx = tid; idx < 25 * 64; idx += 256) {
    int kk = idx >> 6, w = idx & 63;
    int kki = kk / 5, kkj = kk - kki * 5;
    int wp = w + 3 * kkj - 6;
    t7s[kk * 64 + w] = (wp >= 0 && wp < 64) ? cm[kki * 64 + wp] : 0.0f;
  }
  __syncthreads();

  float4 acc[4];
#pragma unroll
  for (int j = 0; j < 4; ++j) acc[j] = make_float4(0.f, 0.f, 0.f, 0.f);
#pragma unroll
  for (int kk = 0; kk < 25; ++kk) {
    float4 tv = *(const float4*)&t7s[kk * 64 + w0];
#pragma unroll
    for (int j = 0; j < 4; ++j) {
      float a = ww[(h0 + j) * 25 + kk];
      acc[j].x = fmaf(a, tv.x, acc[j].x);
      acc[j].y = fmaf(a, tv.y, acc[j].y);
      acc[j].z = fmaf(a, tv.z, acc[j].z);
      acc[j].w = fmaf(a, tv.w, acc[j].w);
    }
  }

  int hpb = 3 * ki - 6, wpb = 3 * kj - 6;
  float pm[4] = {-3.4e38f, -3.4e38f, -3.4e38f, -3.4e38f};
#pragma unroll
  for (int j = 0; j < 4; ++j) {
    int hp = h0 + j + hpb;
    float av[4] = {acc[j].x, acc[j].y, acc[j].z, acc[j].w};
#pragma unroll
    for (int e = 0; e < 4; ++e) {
      int wp = w0 + e + wpb;
      float t6v = (hp >= 0 && hp < 64 && wp >= 0 && wp < 64)
                      ? s5[hp * 64 + wp] : 0.0f;
      float xg = av[e];
      float gl = 0.5f * xg * (1.0f + erff(xg * 0.70710678118654752f));
      pm[e] = fmaxf(pm[e], t6v + gl);
    }
  }
  __syncthreads();
  float* red = t7s;
#pragma unroll
  for (int e = 0; e < 4; ++e) red[rg * 64 + w0 + e] = pm[e];
  __syncthreads();
  if (tid < 64) {
    float m = -3.4e38f;
#pragma unroll
    for (int g = 0; g < 16; ++g) m = fmaxf(m, red[g * 64 + tid]);
    part[(n * KT + k) * 64 + tid] = m;
  }
}

// ---------------------------------------------------------------------------
// KD: t17 recomputed per block from part + output.
// ---------------------------------------------------------------------------
__global__ __launch_bounds__(256) void kd_out(
    const float* __restrict__ part, const float* __restrict__ t13,
    const float* __restrict__ W18, float* __restrict__ out) {
  int bid = blockIdx.x, tid = threadIdx.x;
  int n = bid >> 5, cg8 = bid & 31;
  __shared__ float ps[1600];
  __shared__ float Mb[64];
  __shared__ float t17b[64];
  __shared__ float t13s[4096];
  const float* pp = part + (size_t)n * KT * 64;
  for (int i = tid; i < 1600; i += 256) ps[i] = pp[i];
  const float4* t13v = (const float4*)(t13 + (size_t)n * HW);
  float4* t13sv = (float4*)t13s;
#pragma unroll
  for (int i = 0; i < 4; ++i) t13sv[i * 256 + tid] = t13v[i * 256 + tid];
  __syncthreads();
  if (tid < 64) {
    float m = -3.4e38f;
#pragma unroll
    for (int t = 0; t < KT; ++t) m = fmaxf(m, ps[t * 64 + tid]);
    Mb[tid] = expf(m);
  }
  __syncthreads();
  if (tid < 64) {
    float s = 0.f;
#pragma unroll
    for (int j = 0; j < 7; ++j) {
      int wp = tid + 3 * j - 9;
      if (wp >= 0 && wp < 64) s += Mb[wp];
    }
    t17b[tid] = s * (1.0f / 7.0f);
  }
  __syncthreads();
  const float4* t17v = (const float4*)t17b;
#pragma unroll
  for (int i = 0; i < 8; ++i) {
    int c = cg8 * 8 + i;
    float4* outv = (float4*)(out + (size_t)(n * 256 + c) * HW);
#pragma unroll
    for (int it = 0; it < 4; ++it) {
      int idx = it * 256 + tid;
      int h = idx >> 4;
      int w4 = idx & 15;
      float w18 = W18[c * 64 + h];
      float4 a = t13sv[idx];
      float4 tt = t17v[w4];
      float4 o;
      o.x = a.x - w18 * tt.x;
      o.y = a.y - w18 * tt.y;
      o.z = a.z - w18 * tt.z;
      o.w = a.w - w18 * tt.w;
      outv[idx] = o;
    }
  }
}

// ---------------------------------------------------------------------------
extern "C" void kernel_launch(void* const* d_in, const int* in_sizes, int n_in,
                              void* d_out, int out_size, void* d_ws,
                              size_t ws_size, hipStream_t stream) {
  const float* x   = (const float*)d_in[0];
  const float* W2  = (const float*)d_in[1];
  const float* W8  = (const float*)d_in[2];
  const float* W10 = (const float*)d_in[3];
  const float* W18 = (const float*)d_in[4];
  const float* p4  = (const float*)d_in[5];
  const float* p13 = (const float*)d_in[6];
  float* out = (float*)d_out;

  float* ws    = (float*)d_ws;
  float* w2bar = ws;                   // 256
  float* t3    = w2bar + 256;          // 32*256
  float* t5    = t3 + NB * C;          // 32*4096
  float* t13   = t5 + NB * HW;         // 32*4096
  float* WW    = t13 + NB * HW;        // 1600*25
  float* part  = WW + 40000;           // 32*25*64

  ka_prep<<<dim3(158 + 2048), dim3(256), 0, stream>>>(x, W2, W8, W10, w2bar,
                                                      t3, WW);
  kb_t5t13<<<dim3(NB * 32), dim3(256), 0, stream>>>(x, w2bar, t3, p4, p13,
                                                    t5, t13);
  kc_tile<<<dim3(NB * KT), dim3(256), 0, stream>>>(t5, WW, part);
  kd_out<<<dim3(NB * 32), dim3(256), 0, stream>>>(part, t13, W18, out);
}

// Round 5
// 302.753 us; speedup vs baseline: 1.6355x; 1.0036x over previous
//
#include <hip/hip_runtime.h>
#include <math.h>

#define NB 32
#define C 256
#define H 64
#define W 64
#define HW 4096
#define KT 25  // 25 unfold tiles of 64 o-rows

// Round-3 differential probe: kernel sequence ~98 us, fixed timed overhead
// (harness poison fills) ~201.5 us. Realistic floor ~= 265-275 us total.
// Round-4 profile: ka_prep FETCH=74 MB (x half-L3-resident), LDS 25.6 KB
// capped t3 occupancy at 6 blocks/CU -> this round strips KA's LDS.

// ---------------------------------------------------------------------------
// KA v2: zero LDS. Three independent preps in one launch.
//   bid <  157 : WW[o][kk] = sum_c W10[o][c] * W8[c][kk]  (W8 via L2, no LDS;
//                latency hidden behind the 2048 t3 blocks)
//   bid == 157 : w2bar[c]  = mean_o W2[o][c]
//   bid >= 158 : t3 (relu-max per (n,c) plane), ONE WAVE PER PLANE,
//                now at full 8 blocks/CU occupancy.
// ---------------------------------------------------------------------------
__global__ __launch_bounds__(256) void ka_prep(
    const float* __restrict__ x, const float* __restrict__ W2,
    const float* __restrict__ W8, const float* __restrict__ W10,
    float* __restrict__ w2bar, float* __restrict__ t3,
    float* __restrict__ WW) {
  int bid = blockIdx.x, tid = threadIdx.x;
  if (bid < 157) {
    int idx = bid * 256 + tid;
    if (idx < 40000) {
      int o = idx / 25, kk = idx - o * 25;
      const float* wrow = W10 + (size_t)o * 256;
      float acc = 0.f;
#pragma unroll 8
      for (int c = 0; c < 256; ++c)
        acc = fmaf(wrow[c], W8[c * 25 + kk], acc);
      WW[idx] = acc;
    }
  } else if (bid == 157) {
    float s = 0.f;
#pragma unroll 8
    for (int o = 0; o < 256; ++o) s += W2[o * 256 + tid];
    w2bar[tid] = s * (1.f / 256.f);
  } else {
    int item = (bid - 158) * 4 + (tid >> 6);
    int lane = tid & 63;
    const float4* xv = (const float4*)(x + (size_t)item * HW);
    float m = -3.4e38f;
#pragma unroll
    for (int i = 0; i < 16; ++i) {
      float4 v = xv[i * 64 + lane];
      m = fmaxf(m, fmaxf(fmaxf(v.x, v.y), fmaxf(v.z, v.w)));
    }
#pragma unroll
    for (int off = 32; off > 0; off >>= 1)
      m = fmaxf(m, __shfl_down(m, off, 64));
    if (lane == 0) t3[item] = fmaxf(m, 0.f);
  }
}

// ---------------------------------------------------------------------------
// KB v3: t5/t13 second pass over x (L3-resident), float4 loads, 8-way
// c-split; reduction tail now uses ALL 256 threads (128 on t5, 128 on t9).
// ---------------------------------------------------------------------------
__global__ __launch_bounds__(256) void kb_t5t13(
    const float* __restrict__ x, const float* __restrict__ w2bar,
    const float* __restrict__ t3, const float* __restrict__ p4,
    const float* __restrict__ p13, float* __restrict__ t5,
    float* __restrict__ t13) {
  int bid = blockIdx.x, tid = threadIdx.x;
  int n = bid >> 5;
  int pc = bid & 31;           // 128-position chunk
  int cs = tid >> 5;           // c-slice 0..7
  int l32 = tid & 31;          // float4 index within chunk
  __shared__ float sw[256];
  __shared__ float st[256];
  __shared__ float4 red5[8][32];
  __shared__ float4 red9[8][32];
  sw[tid] = w2bar[tid];
  st[tid] = t3[n * 256 + tid];
  __syncthreads();
  const float4* xq = (const float4*)(x + (size_t)n * C * HW);
  int qbase = pc * 32 + l32;
  float4 a5 = make_float4(0.f, 0.f, 0.f, 0.f);
  float4 a9 = make_float4(0.f, 0.f, 0.f, 0.f);
#pragma unroll 8
  for (int ci = 0; ci < 32; ++ci) {
    int c = cs * 32 + ci;
    float4 v = xq[(size_t)c * 1024 + qbase];
    float wv = sw[c], tv = st[c];
    a5.x = fmaf(wv, fmaxf(v.x, 0.f), a5.x);
    a5.y = fmaf(wv, fmaxf(v.y, 0.f), a5.y);
    a5.z = fmaf(wv, fmaxf(v.z, 0.f), a5.z);
    a5.w = fmaf(wv, fmaxf(v.w, 0.f), a5.w);
    a9.x = fmaf(tv, v.x, a9.x);
    a9.y = fmaf(tv, v.y, a9.y);
    a9.z = fmaf(tv, v.z, a9.z);
    a9.w = fmaf(tv, v.w, a9.w);
  }
  red5[cs][l32] = a5;
  red9[cs][l32] = a9;
  __syncthreads();
  // scalar view: red5/red9 are [8][128] floats; 128 threads per tensor
  const float* r5f = (const float*)red5;
  const float* r9f = (const float*)red9;
  if (tid < 128) {
    float s = r5f[tid];
#pragma unroll
    for (int g = 1; g < 8; ++g) s += r5f[g * 128 + tid];
    int pp = pc * 128 + tid;
    t5[n * HW + pp] = p4[pp] * s;
  } else {
    int j = tid - 128;
    float s = r9f[j];
#pragma unroll
    for (int g = 1; g < 8; ++g) s += r9f[g * 128 + j];
    int pp = pc * 128 + j;
    t13[n * HW + pp] = p13[pp] * s;
  }
}

// ---------------------------------------------------------------------------
// KC: per (n,k) tile: stage t5 + WW rows; unfold col-max -> t7; K=25 GEMM;
// t6 + gelu; max over h -> part[n][k][w].  (proven, unchanged)
// ---------------------------------------------------------------------------
__global__ __launch_bounds__(256) void kc_tile(
    const float* __restrict__ t5g, const float* __restrict__ WW,
    float* __restrict__ part) {
  int n = blockIdx.x / KT;
  int k = blockIdx.x - n * KT;
  int ki = k / 5, kj = k - ki * 5;
  int tid = threadIdx.x;
  int wg = tid & 15, w0 = wg * 4;
  int rg = tid >> 4, h0 = rg * 4;
  __shared__ float s5[HW];
  __shared__ float ww[64 * 25];
  __shared__ float t7s[25 * 64];
  __shared__ float cm[5 * 64];

  const float4* t5v = (const float4*)(t5g + n * HW);
  float4* s5v = (float4*)s5;
#pragma unroll
  for (int i = 0; i < 4; ++i) s5v[i * 256 + tid] = t5v[i * 256 + tid];
  const float* wwsrc = WW + (size_t)k * 64 * 25;
  for (int i = tid; i < 1600; i += 256) ww[i] = wwsrc[i];
  __syncthreads();

  for (int idx = tid; idx < 5 * 64; idx += 256) {
    int kii = idx >> 6, wp = idx & 63;
    int lo = max(0, 3 * kii - 6), hi = min(63, 3 * kii + 57);
    float m = (kii == 2) ? -3.4e38f : 0.0f;
    for (int hp = lo; hp <= hi; ++hp) m = fmaxf(m, s5[hp * 64 + wp]);
    cm[kii * 64 + wp] = m;
  }
  __syncthreads();
  for (int idx = tid; idx < 25 * 64; idx += 256) {
    int kk = idx >> 6, w = idx & 63;
    int kki = kk / 5, kkj = kk - kki * 5;
    int wp = w + 3 * kkj - 6;
    t7s[kk * 64 + w] = (wp >= 0 && wp < 64) ? cm[kki * 64 + wp] : 0.0f;
  }
  __syncthreads();

  float4 acc[4];
#pragma unroll
  for (int j = 0; j < 4; ++j) acc[j] = make_float4(0.f, 0.f, 0.f, 0.f);
#pragma unroll
  for (int kk = 0; kk < 25; ++kk) {
    float4 tv = *(const float4*)&t7s[kk * 64 + w0];
#pragma unroll
    for (int j = 0; j < 4; ++j) {
      float a = ww[(h0 + j) * 25 + kk];
      acc[j].x = fmaf(a, tv.x, acc[j].x);
      acc[j].y = fmaf(a, tv.y, acc[j].y);
      acc[j].z = fmaf(a, tv.z, acc[j].z);
      acc[j].w = fmaf(a, tv.w, acc[j].w);
    }
  }

  int hpb = 3 * ki - 6, wpb = 3 * kj - 6;
  float pm[4] = {-3.4e38f, -3.4e38f, -3.4e38f, -3.4e38f};
#pragma unroll
  for (int j = 0; j < 4; ++j) {
    int hp = h0 + j + hpb;
    float av[4] = {acc[j].x, acc[j].y, acc[j].z, acc[j].w};
#pragma unroll
    for (int e = 0; e < 4; ++e) {
      int wp = w0 + e + wpb;
      float t6v = (hp >= 0 && hp < 64 && wp >= 0 && wp < 64)
                      ? s5[hp * 64 + wp] : 0.0f;
      float xg = av[e];
      float gl = 0.5f * xg * (1.0f + erff(xg * 0.70710678118654752f));
      pm[e] = fmaxf(pm[e], t6v + gl);
    }
  }
  __syncthreads();
  float* red = t7s;
#pragma unroll
  for (int e = 0; e < 4; ++e) red[rg * 64 + w0 + e] = pm[e];
  __syncthreads();
  if (tid < 64) {
    float m = -3.4e38f;
#pragma unroll
    for (int g = 0; g < 16; ++g) m = fmaxf(m, red[g * 64 + tid]);
    part[(n * KT + k) * 64 + tid] = m;
  }
}

// ---------------------------------------------------------------------------
// KD: t17 recomputed per block from part + output.  (proven, unchanged)
// ---------------------------------------------------------------------------
__global__ __launch_bounds__(256) void kd_out(
    const float* __restrict__ part, const float* __restrict__ t13,
    const float* __restrict__ W18, float* __restrict__ out) {
  int bid = blockIdx.x, tid = threadIdx.x;
  int n = bid >> 5, cg8 = bid & 31;
  __shared__ float ps[1600];
  __shared__ float Mb[64];
  __shared__ float t17b[64];
  __shared__ float t13s[4096];
  const float* pp = part + (size_t)n * KT * 64;
  for (int i = tid; i < 1600; i += 256) ps[i] = pp[i];
  const float4* t13v = (const float4*)(t13 + (size_t)n * HW);
  float4* t13sv = (float4*)t13s;
#pragma unroll
  for (int i = 0; i < 4; ++i) t13sv[i * 256 + tid] = t13v[i * 256 + tid];
  __syncthreads();
  if (tid < 64) {
    float m = -3.4e38f;
#pragma unroll
    for (int t = 0; t < KT; ++t) m = fmaxf(m, ps[t * 64 + tid]);
    Mb[tid] = expf(m);
  }
  __syncthreads();
  if (tid < 64) {
    float s = 0.f;
#pragma unroll
    for (int j = 0; j < 7; ++j) {
      int wp = tid + 3 * j - 9;
      if (wp >= 0 && wp < 64) s += Mb[wp];
    }
    t17b[tid] = s * (1.0f / 7.0f);
  }
  __syncthreads();
  const float4* t17v = (const float4*)t17b;
#pragma unroll
  for (int i = 0; i < 8; ++i) {
    int c = cg8 * 8 + i;
    float4* outv = (float4*)(out + (size_t)(n * 256 + c) * HW);
#pragma unroll
    for (int it = 0; it < 4; ++it) {
      int idx = it * 256 + tid;
      int h = idx >> 4;
      int w4 = idx & 15;
      float w18 = W18[c * 64 + h];
      float4 a = t13sv[idx];
      float4 tt = t17v[w4];
      float4 o;
      o.x = a.x - w18 * tt.x;
      o.y = a.y - w18 * tt.y;
      o.z = a.z - w18 * tt.z;
      o.w = a.w - w18 * tt.w;
      outv[idx] = o;
    }
  }
}

// ---------------------------------------------------------------------------
extern "C" void kernel_launch(void* const* d_in, const int* in_sizes, int n_in,
                              void* d_out, int out_size, void* d_ws,
                              size_t ws_size, hipStream_t stream) {
  const float* x   = (const float*)d_in[0];
  const float* W2  = (const float*)d_in[1];
  const float* W8  = (const float*)d_in[2];
  const float* W10 = (const float*)d_in[3];
  const float* W18 = (const float*)d_in[4];
  const float* p4  = (const float*)d_in[5];
  const float* p13 = (const float*)d_in[6];
  float* out = (float*)d_out;

  float* ws    = (float*)d_ws;
  float* w2bar = ws;                   // 256
  float* t3    = w2bar + 256;          // 32*256
  float* t5    = t3 + NB * C;          // 32*4096
  float* t13   = t5 + NB * HW;         // 32*4096
  float* WW    = t13 + NB * HW;        // 1600*25
  float* part  = WW + 40000;           // 32*25*64

  ka_prep<<<dim3(158 + 2048), dim3(256), 0, stream>>>(x, W2, W8, W10, w2bar,
                                                      t3, WW);
  kb_t5t13<<<dim3(NB * 32), dim3(256), 0, stream>>>(x, w2bar, t3, p4, p13,
                                                    t5, t13);
  kc_tile<<<dim3(NB * KT), dim3(256), 0, stream>>>(t5, WW, part);
  kd_out<<<dim3(NB * 32), dim3(256), 0, stream>>>(part, t13, W18, out);
}